// Round 8
// baseline (525.309 us; speedup 1.0000x reference)
//
#include <hip/hip_runtime.h>
#include <stdint.h>

// ---------------------------------------------------------------------------
// 3-layer GraphSAGE (mean aggregation) on MI355X — fused agg+GEMM, packed-h.
//
// h layers are stored PACKED: one uint32 per element = (bf16_hi<<16)|bf16_lo,
// [N][128] u32 rows (512B) -> gather is ONE scattered stream per edge (same
// as fp32 x) while keeping ~fp32 precision for the split-bf16 MFMA.
//
// Per layer, ONE kernel (k_fused, 512 thr = 8 waves, 64 nodes/block):
//   phase 1: CSR gather-mean, 8 nodes/wave, 4 neighbors in flight,
//            fp32 accum -> LDS tile aggF[64][132]
//   phase 2: out = [agg|h] @ [Wl;Wr] + b, split-bf16 mfma_32x32x16
//            (3-MFMA: ah*bh + ah*bl + al*bh). Wave (wm,wn) of 2x4 grid owns a
//            32x32 output tile. A-frags: LDS (split on the fly) / global row.
//            B-frags: direct from L2-resident pre-split frag-ordered W image.
//   phase 3: epilogue via LDS bounce -> coalesced 64B/thread stores.
// Ping-pong: x(f32,in) -> h1 pk(d_out) -> h2 pk(ws) -> f32 out(d_out).
// No buffer is both read and written by one dispatch.
// ---------------------------------------------------------------------------

using bf16x8 = __attribute__((ext_vector_type(8))) __bf16;
using f32x16 = __attribute__((ext_vector_type(16))) float;

__device__ inline unsigned short f2bf(float v) {           // RNE f32->bf16
    uint32_t u = __float_as_uint(v);
    uint32_t r = u + 0x7FFF + ((u >> 16) & 1);
    return (unsigned short)(r >> 16);
}
__device__ inline float bf2f(unsigned short h) {
    return __uint_as_float(((uint32_t)h) << 16);
}
__device__ inline float uf(uint32_t u) { return __uint_as_float(u); }
__device__ inline uint32_t packbf(float v) {               // (hi<<16)|lo
    unsigned short hs = f2bf(v);
    unsigned short ls = f2bf(v - bf2f(hs));
    return ((uint32_t)hs << 16) | ls;
}

__device__ inline void split8(const float* v, bf16x8& h, bf16x8& l) {
    #pragma unroll
    for (int j = 0; j < 8; ++j) {
        unsigned short hs = f2bf(v[j]);
        ((unsigned short*)&h)[j] = hs;
        ((unsigned short*)&l)[j] = f2bf(v[j] - bf2f(hs));
    }
}

// ---------------- CSR build ----------------
__global__ void k_hist(const int* __restrict__ dst, int* __restrict__ deg, int E)
{
    int i = blockIdx.x * blockDim.x + threadIdx.x;
    int stride = gridDim.x * blockDim.x;
    for (; i < E; i += stride) atomicAdd(&deg[dst[i]], 1);
}

__global__ __launch_bounds__(1024) void k_scan(const int* __restrict__ deg,
                                               int* __restrict__ rp,
                                               int* __restrict__ cur, int n)
{
    __shared__ int wsum[16];
    __shared__ int carry_s;
    int tid = threadIdx.x, lane = tid & 63, w = tid >> 6;
    if (tid == 0) carry_s = 0;
    __syncthreads();
    for (int base = 0; base < n; base += 4096) {
        int i = base + tid * 4;
        int4 v = make_int4(0, 0, 0, 0);
        if (i + 3 < n) v = *(const int4*)(deg + i);
        else {
            if (i     < n) v.x = deg[i];
            if (i + 1 < n) v.y = deg[i + 1];
            if (i + 2 < n) v.z = deg[i + 2];
            if (i + 3 < n) v.w = deg[i + 3];
        }
        int t = v.x + v.y + v.z + v.w;
        int s = t;
        #pragma unroll
        for (int d = 1; d < 64; d <<= 1) { int u = __shfl_up(s, d); if (lane >= d) s += u; }
        if (lane == 63) wsum[w] = s;
        __syncthreads();
        if (w == 0 && lane < 16) {
            int u = wsum[lane];
            #pragma unroll
            for (int d = 1; d < 16; d <<= 1) { int y = __shfl_up(u, d); if (lane >= d) u += y; }
            wsum[lane] = u;
        }
        __syncthreads();
        int carry = carry_s;
        int off = carry + (w ? wsum[w - 1] : 0) + (s - t);
        int r0 = off, r1 = r0 + v.x, r2 = r1 + v.y, r3 = r2 + v.z;
        if (i + 3 < n) {
            *(int4*)(rp + i)  = make_int4(r0, r1, r2, r3);
            *(int4*)(cur + i) = make_int4(r0, r1, r2, r3);
        } else {
            if (i     < n) { rp[i]     = r0; cur[i]     = r0; }
            if (i + 1 < n) { rp[i + 1] = r1; cur[i + 1] = r1; }
            if (i + 2 < n) { rp[i + 2] = r2; cur[i + 2] = r2; }
            if (i + 3 < n) { rp[i + 3] = r3; cur[i + 3] = r3; }
        }
        __syncthreads();
        if (tid == 1023) carry_s = carry + wsum[15];
    }
    __syncthreads();
    if (tid == 0) rp[n] = carry_s;
}

__global__ void k_fill(const int* __restrict__ src, const int* __restrict__ dst,
                       int* __restrict__ cur, int* __restrict__ col, int E)
{
    int i = blockIdx.x * blockDim.x + threadIdx.x;
    int stride = gridDim.x * blockDim.x;
    for (; i < E; i += stride) {
        int p = atomicAdd(&cur[dst[i]], 1);
        col[p] = src[i];
    }
}

// ---------------- W -> pre-split frag-ordered image ----------------
// Virtual W = [Wl;Wr] (256x128). 4 chunks (ch): {Wl,Wr} x {k0..63, k64..127}.
// img[ch*16384 + p*8192 + c*64 + kk] = plane_p( W_sel[(ch&1)*64+kk][c] ).
__global__ __launch_bounds__(256) void k_splitW(const float* __restrict__ Wl,
                                                const float* __restrict__ Wr,
                                                unsigned short* __restrict__ img)
{
    int idx = blockIdx.x * 256 + threadIdx.x;       // 32768 total
    int ch  = idx >> 13;
    int rem = idx & 8191;
    int c   = rem >> 6;
    int kk  = rem & 63;
    float v = (ch < 2 ? Wl : Wr)[((ch & 1) * 64 + kk) * 128 + c];
    unsigned short h = f2bf(v);
    img[ch * 16384 + rem]        = h;
    img[ch * 16384 + 8192 + rem] = f2bf(v - bf2f(h));
}

// ---------------- fused layer kernel ----------------
// 512 thr = 8 waves. Phase 2 wave grid: wm = wave>>2 (2 row-halves of 32),
// wn = wave&3 (4 col-tiles of 32). LDS: aggF[64][132] fp32 (33.8KB).
template<int INF32, int OUTF32>
__global__ __launch_bounds__(512) void k_fused(const float* __restrict__ xf,
                                               const uint32_t* __restrict__ inP,
                                               const int* __restrict__ rp,
                                               const int* __restrict__ col,
                                               const unsigned short* __restrict__ wimg,
                                               const float* __restrict__ bias,
                                               float* __restrict__ outF,
                                               uint32_t* __restrict__ outP,
                                               int relu, int nNodes)
{
    __shared__ float aggF[64 * 132];
    const int tid  = threadIdx.x;
    const int wave = tid >> 6, l = tid & 63;
    const int lh   = l >> 5, l31 = l & 31;
    const int wm = wave >> 2, wn = wave & 3;
    const int m0w = wm * 32;
    const int node0 = blockIdx.x * 64;

    // ---- phase 1: gather-mean, 8 nodes per wave, lane owns dims 2l,2l+1 ----
    #pragma unroll 1
    for (int j = 0; j < 8; ++j) {
        const int nl = wave * 8 + j;
        const int n  = node0 + nl;
        int s = 0, e = 0;
        if (n < nNodes) { s = rp[n]; e = rp[n + 1]; }
        float a0 = 0.f, a1 = 0.f, b0 = 0.f, b1 = 0.f;
        float c0a = 0.f, c1a = 0.f, d0a = 0.f, d1a = 0.f;
        int i = s;
        if (INF32) {
            for (; i + 4 <= e; i += 4) {
                int e0 = col[i], e1 = col[i+1], e2 = col[i+2], e3 = col[i+3];
                float2 v0 = *(const float2*)(xf + (size_t)e0 * 128 + 2 * l);
                float2 v1 = *(const float2*)(xf + (size_t)e1 * 128 + 2 * l);
                float2 v2 = *(const float2*)(xf + (size_t)e2 * 128 + 2 * l);
                float2 v3 = *(const float2*)(xf + (size_t)e3 * 128 + 2 * l);
                a0 += v0.x; a1 += v0.y; b0 += v1.x; b1 += v1.y;
                c0a += v2.x; c1a += v2.y; d0a += v3.x; d1a += v3.y;
            }
            for (; i < e; ++i) {
                float2 v0 = *(const float2*)(xf + (size_t)col[i] * 128 + 2 * l);
                a0 += v0.x; a1 += v0.y;
            }
        } else {
            for (; i + 4 <= e; i += 4) {
                int e0 = col[i], e1 = col[i+1], e2 = col[i+2], e3 = col[i+3];
                uint2 u0 = *(const uint2*)(inP + (size_t)e0 * 128 + 2 * l);
                uint2 u1 = *(const uint2*)(inP + (size_t)e1 * 128 + 2 * l);
                uint2 u2 = *(const uint2*)(inP + (size_t)e2 * 128 + 2 * l);
                uint2 u3 = *(const uint2*)(inP + (size_t)e3 * 128 + 2 * l);
                a0 += uf(u0.x & 0xffff0000u) + uf(u0.x << 16);
                a1 += uf(u0.y & 0xffff0000u) + uf(u0.y << 16);
                b0 += uf(u1.x & 0xffff0000u) + uf(u1.x << 16);
                b1 += uf(u1.y & 0xffff0000u) + uf(u1.y << 16);
                c0a += uf(u2.x & 0xffff0000u) + uf(u2.x << 16);
                c1a += uf(u2.y & 0xffff0000u) + uf(u2.y << 16);
                d0a += uf(u3.x & 0xffff0000u) + uf(u3.x << 16);
                d1a += uf(u3.y & 0xffff0000u) + uf(u3.y << 16);
            }
            for (; i < e; ++i) {
                uint2 u0 = *(const uint2*)(inP + (size_t)col[i] * 128 + 2 * l);
                a0 += uf(u0.x & 0xffff0000u) + uf(u0.x << 16);
                a1 += uf(u0.y & 0xffff0000u) + uf(u0.y << 16);
            }
        }
        float inv = (e > s) ? (1.f / (float)(e - s)) : 0.f;
        float2 o;
        o.x = ((a0 + b0) + (c0a + d0a)) * inv;
        o.y = ((a1 + b1) + (c1a + d1a)) * inv;
        *(float2*)&aggF[nl * 132 + 2 * l] = o;
    }
    __syncthreads();

    // ---- phase 2: split-bf16 MFMA, barrier-free loop ----
    f32x16 acc;
    #pragma unroll
    for (int i = 0; i < 16; ++i) acc[i] = 0.f;

    const int rowA_loc  = m0w + l31;
    const int rowA_glob = min(node0 + rowA_loc, nNodes - 1);
    const int c = wn * 32 + l31;                  // this wave's output col

    #pragma unroll
    for (int ch = 0; ch < 4; ++ch) {
        const unsigned short* wb = wimg + ch * 16384;
        #pragma unroll
        for (int ks = 0; ks < 4; ++ks) {
            const int sg   = ks * 2 + lh;
            const int koff = (ch & 1) * 64 + sg * 8;
            bf16x8 a_h, a_l;
            if (ch < 2) {
                float v[8];
                const float* p = &aggF[rowA_loc * 132 + koff];
                *(float4*)v       = *(const float4*)p;
                *(float4*)(v + 4) = *(const float4*)(p + 4);
                split8(v, a_h, a_l);
            } else if (INF32) {
                float v[8];
                const float* p = xf + (size_t)rowA_glob * 128 + koff;
                *(float4*)v       = *(const float4*)p;
                *(float4*)(v + 4) = *(const float4*)(p + 4);
                split8(v, a_h, a_l);
            } else {
                const uint32_t* p = inP + (size_t)rowA_glob * 128 + koff;
                uint4 q0 = *(const uint4*)p;
                uint4 q1 = *(const uint4*)(p + 4);
                uint32_t q[8] = {q0.x, q0.y, q0.z, q0.w, q1.x, q1.y, q1.z, q1.w};
                #pragma unroll
                for (int jj = 0; jj < 8; ++jj) {
                    ((unsigned short*)&a_h)[jj] = (unsigned short)(q[jj] >> 16);
                    ((unsigned short*)&a_l)[jj] = (unsigned short)(q[jj] & 0xffffu);
                }
            }
            bf16x8 b_h = *(const bf16x8*)(wb + c * 64 + sg * 8);
            bf16x8 b_l = *(const bf16x8*)(wb + 8192 + c * 64 + sg * 8);
            acc = __builtin_amdgcn_mfma_f32_32x32x16_bf16(a_h, b_h, acc, 0, 0, 0);
            acc = __builtin_amdgcn_mfma_f32_32x32x16_bf16(a_h, b_l, acc, 0, 0, 0);
            acc = __builtin_amdgcn_mfma_f32_32x32x16_bf16(a_l, b_h, acc, 0, 0, 0);
        }
    }

    // ---- phase 3: epilogue via LDS bounce -> coalesced stores ----
    __syncthreads();                    // all aggF frag reads done
    const float bv = bias[c];
    #pragma unroll
    for (int reg = 0; reg < 16; ++reg) {
        int row = (reg & 3) + 8 * (reg >> 2) + 4 * lh;
        float v = acc[reg] + bv;
        if (relu) v = fmaxf(v, 0.f);
        aggF[(m0w + row) * 132 + c] = v;
    }
    __syncthreads();
    {
        const int rl = tid >> 3;                 // 0..63
        const int gn = node0 + rl;
        if (gn < nNodes) {
            const int cq = (tid & 7) * 16;       // 16 cols per thread
            const float* p = &aggF[rl * 132 + cq];
            if (OUTF32) {
                float* o = outF + (size_t)gn * 128 + cq;
                #pragma unroll
                for (int q = 0; q < 4; ++q)
                    *(float4*)(o + q * 4) = *(const float4*)(p + q * 4);
            } else {
                uint32_t* o = outP + (size_t)gn * 128 + cq;
                #pragma unroll
                for (int g = 0; g < 4; ++g) {
                    float v[4];
                    *(float4*)v = *(const float4*)(p + g * 4);
                    uint4 u;
                    u.x = packbf(v[0]); u.y = packbf(v[1]);
                    u.z = packbf(v[2]); u.w = packbf(v[3]);
                    *(uint4*)(o + g * 4) = u;
                }
            }
        }
    }
}

extern "C" void kernel_launch(void* const* d_in, const int* in_sizes, int n_in,
                              void* d_out, int out_size, void* d_ws, size_t ws_size,
                              hipStream_t stream)
{
    const float* x   = (const float*)d_in[0];
    const int*   ei  = (const int*)d_in[1];
    const float* Wl1 = (const float*)d_in[2];
    const float* b1  = (const float*)d_in[3];
    const float* Wr1 = (const float*)d_in[4];
    const float* Wl2 = (const float*)d_in[5];
    const float* b2  = (const float*)d_in[6];
    const float* Wr2 = (const float*)d_in[7];
    const float* Wl3 = (const float*)d_in[8];
    const float* b3  = (const float*)d_in[9];
    const float* Wr3 = (const float*)d_in[10];

    int N = in_sizes[0] / 128;
    int E = in_sizes[1] / 2;
    const int* srcp = ei;
    const int* dstp = ei + E;
    size_t P = (size_t)N * 128;            // elements per feature matrix

    // ws layout: packed h2 + CSR ints + 3 W images  (~29 MB)
    uint32_t* Hpk = (uint32_t*)d_ws;                // h2 packed [N][128] u32
    int* deg = (int*)(Hpk + P);
    int* rp  = deg + ((N + 3) & ~3);
    int* cur = rp + ((N + 4) & ~3);
    int* col = cur + ((N + 3) & ~3);
    unsigned short* Wimg = (unsigned short*)(col + ((E + 3) & ~3));  // 3 x 65536

    // d_out: packed h1 for layers 1-2, final fp32 output for layer 3
    uint32_t* Opk = (uint32_t*)d_out;
    float* out = (float*)d_out;

    hipMemsetAsync(deg, 0, (size_t)N * sizeof(int), stream);
    k_hist<<<1024, 256, 0, stream>>>(dstp, deg, E);
    k_scan<<<1, 1024, 0, stream>>>(deg, rp, cur, N);
    k_fill<<<1024, 256, 0, stream>>>(srcp, dstp, cur, col, E);

    k_splitW<<<128, 256, 0, stream>>>(Wl1, Wr1, Wimg);
    k_splitW<<<128, 256, 0, stream>>>(Wl2, Wr2, Wimg + 65536);
    k_splitW<<<128, 256, 0, stream>>>(Wl3, Wr3, Wimg + 131072);

    int gb = (N + 63) / 64;
    // layer 1: reads x (f32), writes packed h1 (d_out)
    k_fused<1, 0><<<gb, 512, 0, stream>>>(x, nullptr, rp, col,
                                          Wimg, b1, nullptr, Opk, 1, N);
    // layer 2: reads packed h1 (d_out), writes packed h2 (ws)
    k_fused<0, 0><<<gb, 512, 0, stream>>>(nullptr, Opk, rp, col,
                                          Wimg + 65536, b2, nullptr, Hpk, 1, N);
    // layer 3: reads packed h2 (ws), writes fp32 out (d_out)
    k_fused<0, 1><<<gb, 512, 0, stream>>>(nullptr, Hpk, rp, col,
                                          Wimg + 131072, b3, out, nullptr, 0, N);
}

// Round 11
// 415.917 us; speedup vs baseline: 1.2630x; 1.2630x over previous
//
#include <hip/hip_runtime.h>
#include <hip/hip_fp16.h>
#include <stdint.h>

// ---------------------------------------------------------------------------
// 3-layer GraphSAGE (mean aggregation) on MI355X — fp16-feature edition.
//
// Evidence (R6/R8): the CSR gather is BW-walled (~3 TB/s effective for random
// 512B rows; occupancy up 40% -> 0% faster). Only lever: bytes/edge.
// All feature matrices live as fp16 [N][128] rows (256B) -> gather traffic
// halves. fp16 rel err 2^-11; fp32 accumulation everywhere; GEMM is single
// mfma_f32_32x32x16_f16 (no split needed).
//
// Per layer, ONE kernel (k_fused, 256 thr = 4 waves, 64 nodes/block):
//   phase 1: CSR gather-mean (256B fp16 rows), 16 nodes/wave, 4-deep unroll,
//            fp32 accum -> LDS tile aggF[64][132]
//   phase 2: out = [agg|h] @ [Wl;Wr] + b, fp16 MFMA, fp32 acc.
//            Wave (wm,wn) of 2x2 grid owns 32 rows x 64 cols (2 acc tiles).
//            A-frags: LDS (cvt on the fly) / global fp16 row.
//            B-frags: direct from L2-resident frag-ordered fp16 W image.
//   phase 3: epilogue via LDS bounce -> coalesced stores (fp16 h / fp32 out).
// Ping-pong: x->fp16 Xh(ws) -> h1(d_out) -> h2(ws, reuses Xh) -> f32(d_out).
// No buffer is both read and written by one dispatch.
// ---------------------------------------------------------------------------

using f16x8  = __attribute__((ext_vector_type(8))) _Float16;
using f32x16 = __attribute__((ext_vector_type(16))) float;

// ---------------- CSR build ----------------
__global__ void k_hist(const int* __restrict__ dst, int* __restrict__ deg, int E)
{
    int i = blockIdx.x * blockDim.x + threadIdx.x;
    int stride = gridDim.x * blockDim.x;
    for (; i < E; i += stride) atomicAdd(&deg[dst[i]], 1);
}

__global__ __launch_bounds__(1024) void k_scan(const int* __restrict__ deg,
                                               int* __restrict__ rp,
                                               int* __restrict__ cur, int n)
{
    __shared__ int wsum[16];
    __shared__ int carry_s;
    int tid = threadIdx.x, lane = tid & 63, w = tid >> 6;
    if (tid == 0) carry_s = 0;
    __syncthreads();
    for (int base = 0; base < n; base += 4096) {
        int i = base + tid * 4;
        int4 v = make_int4(0, 0, 0, 0);
        if (i + 3 < n) v = *(const int4*)(deg + i);
        else {
            if (i     < n) v.x = deg[i];
            if (i + 1 < n) v.y = deg[i + 1];
            if (i + 2 < n) v.z = deg[i + 2];
            if (i + 3 < n) v.w = deg[i + 3];
        }
        int t = v.x + v.y + v.z + v.w;
        int s = t;
        #pragma unroll
        for (int d = 1; d < 64; d <<= 1) { int u = __shfl_up(s, d); if (lane >= d) s += u; }
        if (lane == 63) wsum[w] = s;
        __syncthreads();
        if (w == 0 && lane < 16) {
            int u = wsum[lane];
            #pragma unroll
            for (int d = 1; d < 16; d <<= 1) { int y = __shfl_up(u, d); if (lane >= d) u += y; }
            wsum[lane] = u;
        }
        __syncthreads();
        int carry = carry_s;
        int off = carry + (w ? wsum[w - 1] : 0) + (s - t);
        int r0 = off, r1 = r0 + v.x, r2 = r1 + v.y, r3 = r2 + v.z;
        if (i + 3 < n) {
            *(int4*)(rp + i)  = make_int4(r0, r1, r2, r3);
            *(int4*)(cur + i) = make_int4(r0, r1, r2, r3);
        } else {
            if (i     < n) { rp[i]     = r0; cur[i]     = r0; }
            if (i + 1 < n) { rp[i + 1] = r1; cur[i + 1] = r1; }
            if (i + 2 < n) { rp[i + 2] = r2; cur[i + 2] = r2; }
            if (i + 3 < n) { rp[i + 3] = r3; cur[i + 3] = r3; }
        }
        __syncthreads();
        if (tid == 1023) carry_s = carry + wsum[15];
    }
    __syncthreads();
    if (tid == 0) rp[n] = carry_s;
}

__global__ void k_fill(const int* __restrict__ src, const int* __restrict__ dst,
                       int* __restrict__ cur, int* __restrict__ col, int E)
{
    int i = blockIdx.x * blockDim.x + threadIdx.x;
    int stride = gridDim.x * blockDim.x;
    for (; i < E; i += stride) {
        int p = atomicAdd(&cur[dst[i]], 1);
        col[p] = src[i];
    }
}

// ---------------- converters ----------------
// x fp32 -> fp16 rows.
__global__ __launch_bounds__(256) void k_cvtX(const float* __restrict__ x,
                                              __half* __restrict__ o, int total4)
{
    int i = blockIdx.x * blockDim.x + threadIdx.x;
    int stride = gridDim.x * blockDim.x;
    for (; i < total4; i += stride) {
        float4 v = ((const float4*)x)[i];
        __half2 a = __floats2half2_rn(v.x, v.y);
        __half2 b = __floats2half2_rn(v.z, v.w);
        union { __half2 h2[2]; uint2 u; } pk;
        pk.h2[0] = a; pk.h2[1] = b;
        *(uint2*)(o + (size_t)i * 4) = pk.u;
    }
}

// W -> frag-ordered fp16 image. Virtual W = [Wl;Wr] (256x128), 4 chunks:
// ch = {Wl,Wr} x {k0..63, k64..127}; img[ch*8192 + c*64 + kk] =
//   W_sel[(ch&1)*64 + kk][c].  B-frag (col c, slice sg) = 8 halves @ c*64+sg*8.
__global__ __launch_bounds__(256) void k_cvtW(const float* __restrict__ Wl,
                                              const float* __restrict__ Wr,
                                              __half* __restrict__ img)
{
    int idx = blockIdx.x * 256 + threadIdx.x;       // 32768 total
    int ch  = idx >> 13;
    int rem = idx & 8191;
    int c   = rem >> 6;
    int kk  = rem & 63;
    float v = (ch < 2 ? Wl : Wr)[((ch & 1) * 64 + kk) * 128 + c];
    img[ch * 8192 + rem] = __float2half_rn(v);
}

// ---------------- fused layer kernel ----------------
// 256 thr = 4 waves; wave grid 2x2: wm=wave>>1 (32-row half), wn=wave&1
// (64-col half, 2 acc tiles). LDS: aggF[64][132] fp32 (33.8KB).
template<int OUTF32>
__global__ __launch_bounds__(256) void k_fused(const __half* __restrict__ inH,
                                               const int* __restrict__ rp,
                                               const int* __restrict__ col,
                                               const __half* __restrict__ wimg,
                                               const float* __restrict__ bias,
                                               float* __restrict__ outF,
                                               __half* __restrict__ outH,
                                               int relu, int nNodes)
{
    __shared__ float aggF[64 * 132];
    const int tid  = threadIdx.x;
    const int wave = tid >> 6, l = tid & 63;
    const int lh   = l >> 5, l31 = l & 31;
    const int wm = wave >> 1, wn = wave & 1;
    const int m0w = wm * 32;
    const int node0 = blockIdx.x * 64;

    // ---- phase 1: gather-mean, 16 nodes/wave, lane owns dims 2l,2l+1 ----
    #pragma unroll 1
    for (int j = 0; j < 16; ++j) {
        const int nl = wave * 16 + j;
        const int n  = node0 + nl;
        int s = 0, e = 0;
        if (n < nNodes) { s = rp[n]; e = rp[n + 1]; }
        float a0 = 0.f, a1 = 0.f, b0 = 0.f, b1 = 0.f;
        float c0a = 0.f, c1a = 0.f, d0a = 0.f, d1a = 0.f;
        int i = s;
        for (; i + 4 <= e; i += 4) {
            int e0 = col[i], e1 = col[i+1], e2 = col[i+2], e3 = col[i+3];
            __half2 v0 = *(const __half2*)(inH + (size_t)e0 * 128 + 2 * l);
            __half2 v1 = *(const __half2*)(inH + (size_t)e1 * 128 + 2 * l);
            __half2 v2 = *(const __half2*)(inH + (size_t)e2 * 128 + 2 * l);
            __half2 v3 = *(const __half2*)(inH + (size_t)e3 * 128 + 2 * l);
            float2 f0 = __half22float2(v0);
            float2 f1 = __half22float2(v1);
            float2 f2 = __half22float2(v2);
            float2 f3 = __half22float2(v3);
            a0 += f0.x; a1 += f0.y; b0 += f1.x; b1 += f1.y;
            c0a += f2.x; c1a += f2.y; d0a += f3.x; d1a += f3.y;
        }
        for (; i < e; ++i) {
            float2 f0 = __half22float2(*(const __half2*)(inH + (size_t)col[i] * 128 + 2 * l));
            a0 += f0.x; a1 += f0.y;
        }
        float inv = (e > s) ? (1.f / (float)(e - s)) : 0.f;
        float2 o;
        o.x = ((a0 + b0) + (c0a + d0a)) * inv;
        o.y = ((a1 + b1) + (c1a + d1a)) * inv;
        *(float2*)&aggF[nl * 132 + 2 * l] = o;
    }
    __syncthreads();

    // ---- phase 2: fp16 MFMA, fp32 acc, barrier-free loop ----
    f32x16 acc0, acc1;
    #pragma unroll
    for (int i = 0; i < 16; ++i) { acc0[i] = 0.f; acc1[i] = 0.f; }

    const int rowA_loc  = m0w + l31;
    const int rowA_glob = min(node0 + rowA_loc, nNodes - 1);
    const int c0 = wn * 64 + l31, c1 = c0 + 32;

    #pragma unroll
    for (int ch = 0; ch < 4; ++ch) {
        const __half* wb = wimg + ch * 8192;
        #pragma unroll
        for (int ks = 0; ks < 4; ++ks) {
            const int sg   = ks * 2 + lh;
            const int koff = (ch & 1) * 64 + sg * 8;
            f16x8 a;
            if (ch < 2) {
                float v[8];
                const float* p = &aggF[rowA_loc * 132 + koff];
                *(float4*)v       = *(const float4*)p;
                *(float4*)(v + 4) = *(const float4*)(p + 4);
                #pragma unroll
                for (int jj = 0; jj < 8; ++jj) a[jj] = (_Float16)v[jj];
            } else {
                a = *(const f16x8*)(const void*)(inH + (size_t)rowA_glob * 128 + koff);
            }
            f16x8 b0 = *(const f16x8*)(const void*)(wb + c0 * 64 + sg * 8);
            f16x8 b1 = *(const f16x8*)(const void*)(wb + c1 * 64 + sg * 8);
            acc0 = __builtin_amdgcn_mfma_f32_32x32x16_f16(a, b0, acc0, 0, 0, 0);
            acc1 = __builtin_amdgcn_mfma_f32_32x32x16_f16(a, b1, acc1, 0, 0, 0);
        }
    }

    // ---- phase 3: epilogue via LDS bounce -> coalesced stores ----
    __syncthreads();                    // all aggF frag reads done
    const float bv0 = bias[c0];
    const float bv1 = bias[c1];
    #pragma unroll
    for (int reg = 0; reg < 16; ++reg) {
        int row = (reg & 3) + 8 * (reg >> 2) + 4 * lh;
        float v0 = acc0[reg] + bv0;
        float v1 = acc1[reg] + bv1;
        if (relu) { v0 = fmaxf(v0, 0.f); v1 = fmaxf(v1, 0.f); }
        aggF[(m0w + row) * 132 + c0] = v0;
        aggF[(m0w + row) * 132 + c1] = v1;
    }
    __syncthreads();
    {
        const int rl = tid >> 2;                 // 0..63
        const int gn = node0 + rl;
        if (gn < nNodes) {
            const int cq = (tid & 3) * 32;       // 32 cols per thread
            const float* p = &aggF[rl * 132 + cq];
            if (OUTF32) {
                float* o = outF + (size_t)gn * 128 + cq;
                #pragma unroll
                for (int q = 0; q < 8; ++q)
                    *(float4*)(o + q * 4) = *(const float4*)(p + q * 4);
            } else {
                __half* o = outH + (size_t)gn * 128 + cq;
                #pragma unroll
                for (int g = 0; g < 4; ++g) {    // 8 cols per group -> 16B
                    float v[8];
                    *(float4*)v       = *(const float4*)(p + g * 8);
                    *(float4*)(v + 4) = *(const float4*)(p + g * 8 + 4);
                    union { __half2 h2[4]; uint4 u; } pk;
                    pk.h2[0] = __floats2half2_rn(v[0], v[1]);
                    pk.h2[1] = __floats2half2_rn(v[2], v[3]);
                    pk.h2[2] = __floats2half2_rn(v[4], v[5]);
                    pk.h2[3] = __floats2half2_rn(v[6], v[7]);
                    *(uint4*)(o + g * 8) = pk.u;
                }
            }
        }
    }
}

extern "C" void kernel_launch(void* const* d_in, const int* in_sizes, int n_in,
                              void* d_out, int out_size, void* d_ws, size_t ws_size,
                              hipStream_t stream)
{
    const float* x   = (const float*)d_in[0];
    const int*   ei  = (const int*)d_in[1];
    const float* Wl1 = (const float*)d_in[2];
    const float* b1  = (const float*)d_in[3];
    const float* Wr1 = (const float*)d_in[4];
    const float* Wl2 = (const float*)d_in[5];
    const float* b2  = (const float*)d_in[6];
    const float* Wr2 = (const float*)d_in[7];
    const float* Wl3 = (const float*)d_in[8];
    const float* b3  = (const float*)d_in[9];
    const float* Wr3 = (const float*)d_in[10];

    int N = in_sizes[0] / 128;
    int E = in_sizes[1] / 2;
    const int* srcp = ei;
    const int* dstp = ei + E;
    size_t P = (size_t)N * 128;            // elements per feature matrix

    // ws layout: fp16 Xh (reused as h2) + CSR ints + 3 W images (~16 MB)
    __half* Xh = (__half*)d_ws;                     // x fp16, later h2
    int* deg = (int*)(Xh + P);
    int* rp  = deg + ((N + 3) & ~3);
    int* cur = rp + ((N + 4) & ~3);
    int* col = cur + ((N + 3) & ~3);
    __half* Wimg = (__half*)(col + ((E + 3) & ~3)); // 3 x 32768 halves

    // d_out: fp16 h1 for layers 1-2, final fp32 output for layer 3
    __half* Oh = (__half*)d_out;
    float* out = (float*)d_out;

    hipMemsetAsync(deg, 0, (size_t)N * sizeof(int), stream);
    k_hist<<<1024, 256, 0, stream>>>(dstp, deg, E);
    k_scan<<<1, 1024, 0, stream>>>(deg, rp, cur, N);
    k_fill<<<1024, 256, 0, stream>>>(srcp, dstp, cur, col, E);

    k_cvtX<<<512, 256, 0, stream>>>(x, Xh, (int)(P / 4));
    k_cvtW<<<128, 256, 0, stream>>>(Wl1, Wr1, Wimg);
    k_cvtW<<<128, 256, 0, stream>>>(Wl2, Wr2, Wimg + 32768);
    k_cvtW<<<128, 256, 0, stream>>>(Wl3, Wr3, Wimg + 65536);

    int gb = (N + 63) / 64;
    // layer 1: reads Xh (fp16 x, ws), writes fp16 h1 (d_out)
    k_fused<0><<<gb, 256, 0, stream>>>(Xh, rp, col, Wimg, b1,
                                       nullptr, Oh, 1, N);
    // layer 2: reads h1 (d_out), writes fp16 h2 (ws, over dead Xh)
    k_fused<0><<<gb, 256, 0, stream>>>(Oh, rp, col, Wimg + 32768, b2,
                                       nullptr, Xh, 1, N);
    // layer 3: reads h2 (ws), writes fp32 out (d_out)
    k_fused<1><<<gb, 256, 0, stream>>>(Xh, rp, col, Wimg + 65536, b3,
                                       out, nullptr, 0, N);
}